// Round 5
// baseline (798.220 us; speedup 1.0000x reference)
//
#include <hip/hip_runtime.h>
#include <hip/hip_bf16.h>
#include <cstddef>

#define RES 256
#define NCH 32
#define NPT 131072   // points per batch
#define NB  4

#define CHUNKS 8     // 32-point chunks per wave (256 points/block)

typedef _Float16 half8 __attribute__((ext_vector_type(8)));
typedef _Float16 half4 __attribute__((ext_vector_type(4)));
typedef float    f32x4 __attribute__((ext_vector_type(4)));

#define FEAT_STRIDE 40    // halves per feat row (32+8 pad, 80B rows)
#define H0_STRIDE   136   // halves per h0 row (128+8 pad, 272B rows)

#define STAGE_SLOT  1024                 // 64 lanes * 16 B
#define STAGE_BYTES (24 * STAGE_SLOT)    // 24576 B per buffer

typedef __attribute__((address_space(3))) void        lds_void_t;
typedef __attribute__((address_space(1))) const void  gbl_cvoid_t;

// ---------------------------------------------------------------------------
// Transpose + fp16 convert + weight prep (unchanged from R11).
// ---------------------------------------------------------------------------
__global__ __launch_bounds__(256) void transpose_prep_kernel(
    const float* __restrict__ in,
    const float* __restrict__ w0, const float* __restrict__ w1,
    _Float16* __restrict__ out,
    _Float16* __restrict__ w0h, _Float16* __restrict__ w1h)
{
    const int bp = blockIdx.y;                 // 0..12
    const int t  = threadIdx.x;

    if (bp == 12) {                            // weight-prep blocks
        const int i = blockIdx.x * 256 + t;
        if (i < 128 * NCH)  w0h[i] = (_Float16)(w0[i] * 16.0f);
        if (i < 128 * 128)  w1h[i] = (_Float16)w1[i];
        return;
    }

    __shared__ _Float16 tileh[NCH][RES + 8];   // 16.5 KB
    const int y = blockIdx.x;                  // 0..255

    const float4* src4 = (const float4*)(in + (size_t)bp * NCH * RES * RES);
    const int lane64 = t & 63;
    const int cq     = t >> 6;                 // 0..3
    #pragma unroll
    for (int i = 0; i < 8; ++i) {
        const int c = cq * 8 + i;
        const float4 v = src4[(size_t)c * (RES * RES / 4) + y * (RES / 4) + lane64];
        half4 h = { (_Float16)v.x, (_Float16)v.y, (_Float16)v.z, (_Float16)v.w };
        *(half4*)&tileh[c][lane64 * 4] = h;
    }
    __syncthreads();

    _Float16* dst = out + ((size_t)bp * RES * RES + (size_t)y * RES) * NCH;
    const int x = t;                           // texel 0..255
    #pragma unroll
    for (int cg = 0; cg < 4; ++cg) {
        half8 h;
        #pragma unroll
        for (int k = 0; k < 8; ++k)
            h[k] = tileh[cg * 8 + k][x];
        *(half8*)&dst[(size_t)x * NCH + cg * 8] = h;
    }
}

// ---------------------------------------------------------------------------
// R16 fused kernel helpers
// ---------------------------------------------------------------------------
__device__ __forceinline__ void load_coords3(
    const float* __restrict__ coords, int gp, float* c3)
{
    c3[0] = coords[(size_t)gp * 3 + 0];
    c3[1] = coords[(size_t)gp * 3 + 1];
    c3[2] = coords[(size_t)gp * 3 + 2];
}

__device__ __forceinline__ void calc_corners(
    float cx, float cy, float cz, int b, int hf, int* offs, float* wgt)
{
    #pragma unroll
    for (int pl = 0; pl < 3; ++pl) {
        const float u = (pl == 0) ? cx : (pl == 1) ? cy : cx;
        const float v = (pl == 0) ? cy : cz;

        const float fx = (u + 1.0f) * 0.5f * (RES - 1);
        const float fy = (v + 1.0f) * 0.5f * (RES - 1);
        const float x0f = floorf(fx), y0f = floorf(fy);
        const float wx = fx - x0f, wy = fy - y0f;
        const int x0 = (int)x0f, y0 = (int)y0f;
        const bool vx1 = (x0 + 1) < RES;
        const bool vy1 = (y0 + 1) < RES;
        const int x1 = vx1 ? x0 + 1 : RES - 1;
        const int y1 = vy1 ? y0 + 1 : RES - 1;

        float w00 = (1.0f - wx) * (1.0f - wy);
        float w01 = wx * (1.0f - wy);
        float w10 = (1.0f - wx) * wy;
        float w11 = wx * wy;
        if (!vx1) { w01 = 0.0f; w11 = 0.0f; }
        if (!vy1) { w10 = 0.0f; w11 = 0.0f; }

        // offset (halves) = ((b*3+pl)*65536 + y*256 + x)*32 + hf*16
        const int pbase = ((b * 3 + pl) << 21) + (hf << 4);
        offs[pl * 4 + 0] = pbase + (y0 << 13) + (x0 << 5);
        offs[pl * 4 + 1] = pbase + (y0 << 13) + (x1 << 5);
        offs[pl * 4 + 2] = pbase + (y1 << 13) + (x0 << 5);
        offs[pl * 4 + 3] = pbase + (y1 << 13) + (x1 << 5);
        wgt[pl * 4 + 0] = w00; wgt[pl * 4 + 1] = w01;
        wgt[pl * 4 + 2] = w10; wgt[pl * 4 + 3] = w11;
    }
}

__device__ __forceinline__ void issue_gathers(
    const _Float16* __restrict__ planesT, const int* offs, unsigned char* stg)
{
    #pragma unroll
    for (int i = 0; i < 12; ++i) {
        const _Float16* cp = planesT + (size_t)(unsigned)offs[i];
        __builtin_amdgcn_global_load_lds(
            (gbl_cvoid_t*)cp,
            (lds_void_t*)(stg + (2 * i) * STAGE_SLOT), 16, 0, 0);
        __builtin_amdgcn_global_load_lds(
            (gbl_cvoid_t*)(cp + 8),
            (lds_void_t*)(stg + (2 * i + 1) * STAGE_SLOT), 16, 0, 0);
    }
}

// Full per-chunk compute: interp (from staged slots, bit-exact FMA chains)
// + feat/h0 in the SAME (consumed) buffer + MFMA MLP + epilogue store.
__device__ __forceinline__ void compute_chunk(
    unsigned char* stg, const float* wgt,
    const half8* w0r, const float* b0v, const float* b1v, const float* w2s,
    const _Float16* __restrict__ w1h, float bias2, int outbase,
    int tid, int l15, int quad, int p, int hf,
    float* __restrict__ out)
{
    _Float16* wbase = (_Float16*)stg;

    // ---- interpolate (identical FMA expressions to R6-R15: bit-exact)
    float prod[16];
    #pragma unroll
    for (int pl = 0; pl < 3; ++pl) {
        half8 c0[4], c1[4];
        #pragma unroll
        for (int c = 0; c < 4; ++c) {
            c0[c] = *(const half8*)&stg[(pl * 8 + 2 * c)     * STAGE_SLOT + tid * 16];
            c1[c] = *(const half8*)&stg[(pl * 8 + 2 * c + 1) * STAGE_SLOT + tid * 16];
        }
        #pragma unroll
        for (int k = 0; k < 8; ++k) {
            const float t0 =
                fmaf((float)c0[3][k], wgt[pl*4+3],
                fmaf((float)c0[2][k], wgt[pl*4+2],
                fmaf((float)c0[1][k], wgt[pl*4+1],
                     (float)c0[0][k] * wgt[pl*4+0])));
            const float t1 =
                fmaf((float)c1[3][k], wgt[pl*4+3],
                fmaf((float)c1[2][k], wgt[pl*4+2],
                fmaf((float)c1[1][k], wgt[pl*4+1],
                     (float)c1[0][k] * wgt[pl*4+0])));
            if (pl == 0) { prod[k] = t0;  prod[8 + k] = t1; }
            else         { prod[k] *= t0; prod[8 + k] *= t1; }
        }
    }

    half8 o0, o1;
    #pragma unroll
    for (int k = 0; k < 8; ++k) {
        o0[k] = (_Float16)(prod[k]     * 256.0f);
        o1[k] = (_Float16)(prod[8 + k] * 256.0f);
    }
    // feat write clobbers slots 0..2 — all 24 slots consumed above
    // (wave-lockstep program order; same LDS object -> no reorder).
    *(half8*)&wbase[p * FEAT_STRIDE + hf * 16 + 0] = o0;
    *(half8*)&wbase[p * FEAT_STRIDE + hf * 16 + 8] = o1;

    // a0 reads: same wave wrote these rows; lgkmcnt orders write->read.
    half8 a0[2];
    #pragma unroll
    for (int mt = 0; mt < 2; ++mt)
        a0[mt] = *(const half8*)&wbase[(mt * 16 + l15) * FEAT_STRIDE + quad * 8];

    // ---- layer 0 (h0 writes clobber feat region; WAR ordered by lgkmcnt)
    #pragma unroll 1
    for (int nt = 0; nt < 8; ++nt) {
        const half8 bfr = w0r[nt];
        f32x4 acc[2];
        #pragma unroll
        for (int mt = 0; mt < 2; ++mt) {
            acc[mt] = (f32x4){0.f, 0.f, 0.f, 0.f};
            acc[mt] = __builtin_amdgcn_mfma_f32_16x16x32_f16(
                a0[mt], bfr, acc[mt], 0, 0, 0);
        }
        #pragma unroll
        for (int mt = 0; mt < 2; ++mt)
            #pragma unroll
            for (int r = 0; r < 4; ++r) {
                const float hval = fmaxf(acc[mt][r] + b0v[nt], 0.0f);
                wbase[(mt * 16 + quad * 4 + r) * H0_STRIDE + nt * 16 + l15]
                    = (_Float16)hval;
            }
    }

    // ---- layer 1 (+ fused layer-2 epilogue)
    half8 a1[2][4];
    #pragma unroll
    for (int mt = 0; mt < 2; ++mt)
        #pragma unroll
        for (int ks = 0; ks < 4; ++ks)
            a1[mt][ks] = *(const half8*)
                &wbase[(mt * 16 + l15) * H0_STRIDE + ks * 32 + quad * 8];

    float part[2][4];
    #pragma unroll
    for (int mt = 0; mt < 2; ++mt)
        #pragma unroll
        for (int r = 0; r < 4; ++r) part[mt][r] = 0.0f;

    #pragma unroll 2
    for (int nt = 0; nt < 8; ++nt) {
        f32x4 acc[2];
        #pragma unroll
        for (int mt = 0; mt < 2; ++mt) acc[mt] = (f32x4){0.f, 0.f, 0.f, 0.f};
        #pragma unroll
        for (int ks = 0; ks < 4; ++ks) {
            const half8 bfr = *(const half8*)
                &w1h[(nt * 16 + l15) * 128 + ks * 32 + quad * 8];
            #pragma unroll
            for (int mt = 0; mt < 2; ++mt)
                acc[mt] = __builtin_amdgcn_mfma_f32_16x16x32_f16(
                    a1[mt][ks], bfr, acc[mt], 0, 0, 0);
        }
        #pragma unroll
        for (int mt = 0; mt < 2; ++mt)
            #pragma unroll
            for (int r = 0; r < 4; ++r)
                part[mt][r] = fmaf(w2s[nt], fmaxf(acc[mt][r] + b1v[nt], 0.0f),
                                   part[mt][r]);
    }

    #pragma unroll
    for (int mt = 0; mt < 2; ++mt)
        #pragma unroll
        for (int r = 0; r < 4; ++r) {
            float s = part[mt][r];
            s += __shfl_xor(s, 1);
            s += __shfl_xor(s, 2);
            s += __shfl_xor(s, 4);
            s += __shfl_xor(s, 8);
            part[mt][r] = s;
        }

    if (l15 == 0) {
        #pragma unroll
        for (int mt = 0; mt < 2; ++mt)
            #pragma unroll
            for (int r = 0; r < 4; ++r)
                out[outbase + mt * 16 + quad * 4 + r] = part[mt][r] + bias2;
    }
}

// ---------------------------------------------------------------------------
// Fused sample + MFMA MLP, one wave per block, software-pipelined chunks.
// R16: each wave processes CHUNKS=8 chunks of 32 points with double-buffered
// DMA staging (stageA/stageB are DISTINCT static LDS objects so alias
// analysis keeps the buffers independent). While chunk c computes out of
// buf[c&1], chunk c+1's 24 global_load_lds gathers are in flight into
// buf[(c+1)&1] — the HBM/L3 gather latency hides under interp+MLP of the
// previous chunk (ILP, since 3 blocks/CU leaves no TLP). vmcnt in-order
// retirement: the manual vmcnt(27) waits exactly for the previous chunk's
// 24 DMAs (the 27 newer ops = 3 coords + 24 next-chunk DMAs stay in
// flight). Coords prefetched two chunks ahead; weights/bias hoisted into
// registers once per block (amortized 8x). Per-point math identical to
// R6-R15 -> bit-exact.
// ---------------------------------------------------------------------------
__global__ __launch_bounds__(64, 1) void fused_kernel(
    const _Float16* __restrict__ planesT,   // [12][256][256][32] f16
    const float* __restrict__ coords,
    const _Float16* __restrict__ w0h,       // [128][32]  (x16)
    const _Float16* __restrict__ w1h,       // [128][128]
    const float* __restrict__ b0, const float* __restrict__ b1,
    const float* __restrict__ w2, const float* __restrict__ b2,
    float* __restrict__ out)
{
    __shared__ __align__(16) unsigned char stageA[STAGE_BYTES];  // 24 KB
    __shared__ __align__(16) unsigned char stageB[STAGE_BYTES];  // 24 KB

    const int tid  = threadIdx.x;           // 0..63 (one wave)
    const int l15  = tid & 15;
    const int quad = tid >> 4;
    const int p    = tid >> 1;              // wave-local point 0..31
    const int hf   = tid & 1;               // channel half
    const int chunk0 = blockIdx.x * CHUNKS;

    // ---- persistent per-lane weights/biases (once per 256 points)
    half8 w0r[8];
    float b0v[8], b1v[8], w2s[8];
    #pragma unroll
    for (int nt = 0; nt < 8; ++nt) {
        w0r[nt] = *(const half8*)&w0h[(nt * 16 + l15) * NCH + quad * 8];
        b0v[nt] = b0[nt * 16 + l15] * 4096.0f;
        b1v[nt] = b1[nt * 16 + l15] * 4096.0f;
        w2s[nt] = w2[nt * 16 + l15] * (1.0f / 4096.0f);
    }
    const float bias2 = b2[0];

    float cA[3], cB[3];            // coords(k) lives in set k&1
    float wgtA[12], wgtB[12];      // wgt(k) lives in set k&1
    int   offs[12];

    // ---- prologue: chunk 0 -> stageA; coords(1) prefetch
    load_coords3(coords, (chunk0 + 0) * 32 + p, cA);
    calc_corners(cA[0], cA[1], cA[2], ((chunk0 + 0) * 32 + p) >> 17, hf,
                 offs, wgtA);
    load_coords3(coords, (chunk0 + 1) * 32 + p, cB);
    issue_gathers(planesT, offs, stageA);

    // STEP(c): uses coords(c+1), preps chunk c+1 -> NXT, computes chunk c.
#define STEP_FULL(C, CUR, NXT, WCUR, WNXT, CO_NEXT, CO_LOAD)                   \
    {                                                                          \
        const int cnx = (C) + 1;                                               \
        calc_corners(CO_NEXT[0], CO_NEXT[1], CO_NEXT[2],                       \
                     ((chunk0 + cnx) * 32 + p) >> 17, hf, offs, WNXT);         \
        const int cpre = ((C) + 2 < CHUNKS) ? (C) + 2 : CHUNKS - 1;            \
        load_coords3(coords, (chunk0 + cpre) * 32 + p, CO_LOAD);               \
        issue_gathers(planesT, offs, NXT);                                     \
        asm volatile("s_waitcnt vmcnt(27)" ::: "memory");                      \
        __builtin_amdgcn_sched_barrier(0);                                     \
        compute_chunk(CUR, WCUR, w0r, b0v, b1v, w2s, w1h, bias2,               \
                      (chunk0 + (C)) * 32, tid, l15, quad, p, hf, out);        \
    }

    #pragma unroll 1
    for (int cc = 0; cc < (CHUNKS - 2) / 2; ++cc) {      // chunks 0..5
        const int c0 = 2 * cc;
        STEP_FULL(c0,     stageA, stageB, wgtA, wgtB, cB, cA);
        STEP_FULL(c0 + 1, stageB, stageA, wgtB, wgtA, cA, cB);
    }
    STEP_FULL(CHUNKS - 2, stageA, stageB, wgtA, wgtB, cB, cA);   // chunk 6
#undef STEP_FULL

    // ---- final chunk: drain and compute
    asm volatile("s_waitcnt vmcnt(0)" ::: "memory");
    __builtin_amdgcn_sched_barrier(0);
    compute_chunk(stageB, wgtB, w0r, b0v, b1v, w2s, w1h, bias2,
                  (chunk0 + CHUNKS - 1) * 32, tid, l15, quad, p, hf, out);
}

// ---------------------------------------------------------------------------
// Fallback (ws too small): round-1 fused fp32 kernel on original layout.
// ---------------------------------------------------------------------------
__global__ __launch_bounds__(256) void fused_fallback(
    const float* __restrict__ planes, const float* __restrict__ coords,
    const float* __restrict__ w0, const float* __restrict__ b0,
    const float* __restrict__ w1, const float* __restrict__ b1,
    const float* __restrict__ w2, const float* __restrict__ b2,
    float* __restrict__ out)
{
    const int t = blockIdx.x * 256 + threadIdx.x;
    const int b = t >> 17;
    const float cx = coords[(size_t)t * 3 + 0];
    const float cy = coords[(size_t)t * 3 + 1];
    const float cz = coords[(size_t)t * 3 + 2];
    float feat[NCH];
    #pragma unroll
    for (int p = 0; p < 3; ++p) {
        const float u = (p == 0) ? cx : (p == 1) ? cy : cx;
        const float v = (p == 0) ? cy : cz;
        const float fx = (u + 1.0f) * 0.5f * (RES - 1);
        const float fy = (v + 1.0f) * 0.5f * (RES - 1);
        const float x0f = floorf(fx), y0f = floorf(fy);
        const float wx = fx - x0f, wy = fy - y0f;
        const int x0 = (int)x0f, y0 = (int)y0f;
        const bool vx1 = (x0 + 1) < RES, vy1 = (y0 + 1) < RES;
        const int x1 = vx1 ? x0 + 1 : RES - 1;
        const int y1 = vy1 ? y0 + 1 : RES - 1;
        float w00 = (1.0f - wx) * (1.0f - wy), w01 = wx * (1.0f - wy);
        float w10 = (1.0f - wx) * wy, w11 = wx * wy;
        if (!vx1) { w01 = 0.0f; w11 = 0.0f; }
        if (!vy1) { w10 = 0.0f; w11 = 0.0f; }
        const float* base = planes + (size_t)(b * 3 + p) * NCH * RES * RES;
        const float* p00 = base + (size_t)y0 * RES + x0;
        const float* p01 = base + (size_t)y0 * RES + x1;
        const float* p10 = base + (size_t)y1 * RES + x0;
        const float* p11 = base + (size_t)y1 * RES + x1;
        #pragma unroll
        for (int c = 0; c < NCH; ++c) {
            const size_t off = (size_t)c * RES * RES;
            float s = p00[off] * w00;
            s = fmaf(p01[off], w01, s);
            s = fmaf(p10[off], w10, s);
            s = fmaf(p11[off], w11, s);
            if (p == 0) feat[c] = s; else feat[c] *= s;
        }
    }
    float h0[128];
    #pragma unroll
    for (int g = 0; g < 128; ++g) {
        const float* wr = w0 + g * NCH;
        float aA = b0[g], aB = 0.0f;
        #pragma unroll
        for (int c = 0; c < NCH; c += 2) {
            aA = fmaf(wr[c], feat[c], aA);
            aB = fmaf(wr[c + 1], feat[c + 1], aB);
        }
        h0[g] = fmaxf(aA + aB, 0.0f);
    }
    float o = b2[0];
    for (int g = 0; g < 128; ++g) {
        const float* wr = w1 + g * 128;
        float aA = b1[g], aB = 0.0f, aC = 0.0f, aD = 0.0f;
        #pragma unroll
        for (int h = 0; h < 128; h += 4) {
            aA = fmaf(wr[h], h0[h], aA);
            aB = fmaf(wr[h + 1], h0[h + 1], aB);
            aC = fmaf(wr[h + 2], h0[h + 2], aC);
            aD = fmaf(wr[h + 3], h0[h + 3], aD);
        }
        o = fmaf(fmaxf((aA + aB) + (aC + aD), 0.0f), w2[g], o);
    }
    out[t] = o;
}

// ---------------------------------------------------------------------------
extern "C" void kernel_launch(void* const* d_in, const int* in_sizes, int n_in,
                              void* d_out, int out_size, void* d_ws, size_t ws_size,
                              hipStream_t stream)
{
    const float* trip   = (const float*)d_in[0];
    const float* coords = (const float*)d_in[1];
    const float* w0     = (const float*)d_in[2];
    const float* b0     = (const float*)d_in[3];
    const float* w1     = (const float*)d_in[4];
    const float* b1     = (const float*)d_in[5];
    const float* w2     = (const float*)d_in[6];
    const float* b2     = (const float*)d_in[7];
    float* out = (float*)d_out;

    const size_t planesTBytes = (size_t)NB * 3 * RES * RES * NCH * 2;   // 50331648
    const size_t w0hBytes = 128 * NCH * 2;                              // 8192
    const size_t w1hBytes = 128 * 128 * 2;                              // 32768
    const size_t needed = planesTBytes + w0hBytes + w1hBytes;

    if (ws_size >= needed) {
        _Float16* planesT = (_Float16*)d_ws;
        _Float16* w0h     = (_Float16*)((char*)d_ws + planesTBytes);
        _Float16* w1h     = (_Float16*)((char*)d_ws + planesTBytes + w0hBytes);

        transpose_prep_kernel<<<dim3(RES, NB * 3 + 1), 256, 0, stream>>>(
            trip, w0, w1, planesT, w0h, w1h);
        fused_kernel<<<(NB * NPT) / (32 * CHUNKS), 64, 0, stream>>>(
            planesT, coords, w0h, w1h, b0, b1, w2, b2, out);
    } else {
        fused_fallback<<<(NB * NPT) / 256, 256, 0, stream>>>(
            trip, coords, w0, b0, w1, b1, w2, b2, out);
    }
}

// Round 6
// 688.312 us; speedup vs baseline: 1.1597x; 1.1597x over previous
//
#include <hip/hip_runtime.h>
#include <hip/hip_bf16.h>
#include <cstddef>

#define RES 256
#define NCH 32
#define NPT 131072   // points per batch
#define NB  4

typedef _Float16 half8 __attribute__((ext_vector_type(8)));
typedef _Float16 half4 __attribute__((ext_vector_type(4)));
typedef float    f32x4 __attribute__((ext_vector_type(4)));

#define FEAT_STRIDE 40    // halves per feat row (32+8 pad, 80B rows)
#define H0_STRIDE   136   // halves per h0 row (128+8 pad, 272B rows)

// R17: per-PLANE staging, 8 slots of 64 lanes x 16B = 8192 B, reused for all
// 3 planes. Slots alias the feat/h0 work region -> total LDS = 8704 B (the
// h0 region size), same as the R0 baseline -> ~10 waves/CU, vs R15's 24.6 KB
// (6 waves/CU) which cancelled the DMA win.
#define STAGE_SLOT  1024
#define LDS_BYTES   8704

typedef __attribute__((address_space(3))) void        lds_void_t;
typedef __attribute__((address_space(1))) const void  gbl_cvoid_t;

// ---------------------------------------------------------------------------
// Transpose + fp16 convert + weight prep (unchanged from R11).
// ---------------------------------------------------------------------------
__global__ __launch_bounds__(256) void transpose_prep_kernel(
    const float* __restrict__ in,
    const float* __restrict__ w0, const float* __restrict__ w1,
    _Float16* __restrict__ out,
    _Float16* __restrict__ w0h, _Float16* __restrict__ w1h)
{
    const int bp = blockIdx.y;                 // 0..12
    const int t  = threadIdx.x;

    if (bp == 12) {                            // weight-prep blocks
        const int i = blockIdx.x * 256 + t;
        if (i < 128 * NCH)  w0h[i] = (_Float16)(w0[i] * 16.0f);
        if (i < 128 * 128)  w1h[i] = (_Float16)w1[i];
        return;
    }

    __shared__ _Float16 tileh[NCH][RES + 8];   // 16.5 KB
    const int y = blockIdx.x;                  // 0..255

    const float4* src4 = (const float4*)(in + (size_t)bp * NCH * RES * RES);
    const int lane64 = t & 63;
    const int cq     = t >> 6;                 // 0..3
    #pragma unroll
    for (int i = 0; i < 8; ++i) {
        const int c = cq * 8 + i;
        const float4 v = src4[(size_t)c * (RES * RES / 4) + y * (RES / 4) + lane64];
        half4 h = { (_Float16)v.x, (_Float16)v.y, (_Float16)v.z, (_Float16)v.w };
        *(half4*)&tileh[c][lane64 * 4] = h;
    }
    __syncthreads();

    _Float16* dst = out + ((size_t)bp * RES * RES + (size_t)y * RES) * NCH;
    const int x = t;                           // texel 0..255
    #pragma unroll
    for (int cg = 0; cg < 4; ++cg) {
        half8 h;
        #pragma unroll
        for (int k = 0; k < 8; ++k)
            h[k] = tileh[cg * 8 + k][x];
        *(half8*)&dst[(size_t)x * NCH + cg * 8] = h;
    }
}

// ---------------------------------------------------------------------------
// R17 helpers
// ---------------------------------------------------------------------------
__device__ __forceinline__ void calc_plane(
    int pl, float cx, float cy, float cz, int b, int hf,
    int* __restrict__ offs, float* __restrict__ wgt)
{
    const float u = (pl == 0) ? cx : (pl == 1) ? cy : cx;
    const float v = (pl == 0) ? cy : cz;

    const float fx = (u + 1.0f) * 0.5f * (RES - 1);
    const float fy = (v + 1.0f) * 0.5f * (RES - 1);
    const float x0f = floorf(fx), y0f = floorf(fy);
    const float wx = fx - x0f, wy = fy - y0f;
    const int x0 = (int)x0f, y0 = (int)y0f;
    const bool vx1 = (x0 + 1) < RES;
    const bool vy1 = (y0 + 1) < RES;
    const int x1 = vx1 ? x0 + 1 : RES - 1;
    const int y1 = vy1 ? y0 + 1 : RES - 1;

    float w00 = (1.0f - wx) * (1.0f - wy);
    float w01 = wx * (1.0f - wy);
    float w10 = (1.0f - wx) * wy;
    float w11 = wx * wy;
    if (!vx1) { w01 = 0.0f; w11 = 0.0f; }
    if (!vy1) { w10 = 0.0f; w11 = 0.0f; }

    // offset (halves) = ((b*3+pl)*65536 + y*256 + x)*32 + hf*16
    const int pbase = ((b * 3 + pl) << 21) + (hf << 4);
    offs[pl * 4 + 0] = pbase + (y0 << 13) + (x0 << 5);
    offs[pl * 4 + 1] = pbase + (y0 << 13) + (x1 << 5);
    offs[pl * 4 + 2] = pbase + (y1 << 13) + (x0 << 5);
    offs[pl * 4 + 3] = pbase + (y1 << 13) + (x1 << 5);
    wgt[pl * 4 + 0] = w00; wgt[pl * 4 + 1] = w01;
    wgt[pl * 4 + 2] = w10; wgt[pl * 4 + 3] = w11;
}

// 8 async DMA gathers for one plane (4 corners x 2 half8) into slots 0..7.
__device__ __forceinline__ void issue_plane(
    const _Float16* __restrict__ planesT, const int* offs4,
    unsigned char* stg)
{
    #pragma unroll
    for (int c = 0; c < 4; ++c) {
        const _Float16* cp = planesT + (size_t)(unsigned)offs4[c];
        __builtin_amdgcn_global_load_lds(
            (gbl_cvoid_t*)cp,
            (lds_void_t*)(stg + (2 * c) * STAGE_SLOT), 16, 0, 0);
        __builtin_amdgcn_global_load_lds(
            (gbl_cvoid_t*)(cp + 8),
            (lds_void_t*)(stg + (2 * c + 1) * STAGE_SLOT), 16, 0, 0);
    }
}

__device__ __forceinline__ void read_slots(
    const unsigned char* stg, int tid, half8* c0, half8* c1)
{
    #pragma unroll
    for (int c = 0; c < 4; ++c) {
        c0[c] = *(const half8*)&stg[(2 * c)     * STAGE_SLOT + tid * 16];
        c1[c] = *(const half8*)&stg[(2 * c + 1) * STAGE_SLOT + tid * 16];
    }
}

// Identical FMA expressions to R6-R16 -> bit-exact.
__device__ __forceinline__ void interp_plane(
    int pl, const half8* c0, const half8* c1, const float* wgt,
    float* __restrict__ prod)
{
    #pragma unroll
    for (int k = 0; k < 8; ++k) {
        const float t0 =
            fmaf((float)c0[3][k], wgt[pl*4+3],
            fmaf((float)c0[2][k], wgt[pl*4+2],
            fmaf((float)c0[1][k], wgt[pl*4+1],
                 (float)c0[0][k] * wgt[pl*4+0])));
        const float t1 =
            fmaf((float)c1[3][k], wgt[pl*4+3],
            fmaf((float)c1[2][k], wgt[pl*4+2],
            fmaf((float)c1[1][k], wgt[pl*4+1],
                 (float)c1[0][k] * wgt[pl*4+0])));
        if (pl == 0) { prod[k] = t0;  prod[8 + k] = t1; }
        else         { prod[k] *= t0; prod[8 + k] *= t1; }
    }
}

// ---------------------------------------------------------------------------
// Fused sample + MFMA MLP, one wave per block, zero barriers.
// R17 = R15's DMA gathers restructured per-plane so LDS returns to the R0
// footprint (8704 B -> ~10 waves/CU). Schedule per plane:
//   issue(pl) ... vmcnt(0) ... ds_read slots ... lgkmcnt(0) ...
//   issue(pl+1) ... FMA(pl)            <- pl+1 flight hides under FMA(pl)
// MLP weights/biases are hoisted to the kernel top so their L2 latency
// hides under corner math instead of the post-gather critical path.
// R16's cross-chunk pipeline is reverted (74K cyc/chunk codegen disaster).
// MFMA 16x16x32 f16 layouts (verified m89/m120 + rounds 3/4/6/7):
//   A: lane holds A[m=lane&15][k=quad*8+j]
//   B: lane holds B[k=quad*8+j][n=lane&15] = W[n][k] row-major 8-contig
//   C/D: col n = lane&15, row m = quad*4+reg
// ---------------------------------------------------------------------------
__global__ __launch_bounds__(64, 1) void fused_kernel(
    const _Float16* __restrict__ planesT,   // [12][256][256][32] f16
    const float* __restrict__ coords,
    const _Float16* __restrict__ w0h,       // [128][32]  (x16)
    const _Float16* __restrict__ w1h,       // [128][128]
    const float* __restrict__ b0, const float* __restrict__ b1,
    const float* __restrict__ w2, const float* __restrict__ b2,
    float* __restrict__ out)
{
    __shared__ __align__(16) unsigned char stage[LDS_BYTES];   // 8704 B
    _Float16* wbase = (_Float16*)stage;     // feat/h0 alias (consumed-before-write)

    const int tid  = threadIdx.x;           // 0..63 (one wave)
    const int l15  = tid & 15;
    const int quad = tid >> 4;
    const int p    = tid >> 1;              // wave-local point 0..31
    const int hf   = tid & 1;               // channel half

    const int gp = blockIdx.x * 32 + p;
    const int b  = gp >> 17;                // NPT = 2^17
    const float cx = coords[(size_t)gp * 3 + 0];
    const float cy = coords[(size_t)gp * 3 + 1];
    const float cz = coords[(size_t)gp * 3 + 2];

    // ---- hoisted MLP params: issue early, consumed only after the gathers.
    half8 w0r[8];
    float b0v[8], b1v[8], w2s[8];
    #pragma unroll
    for (int nt = 0; nt < 8; ++nt) {
        w0r[nt] = *(const half8*)&w0h[(nt * 16 + l15) * NCH + quad * 8];
        b0v[nt] = b0[nt * 16 + l15] * 4096.0f;
        b1v[nt] = b1[nt * 16 + l15] * 4096.0f;
        w2s[nt] = w2[nt * 16 + l15] * (1.0f / 4096.0f);
    }
    const float bias2 = b2[0];
    __builtin_amdgcn_sched_barrier(0);      // pin load issue here (no sinking)

    // ---- corner offsets/weights; plane 0 DMAs issued ASAP
    int   offs[12];
    float wgt[12];
    calc_plane(0, cx, cy, cz, b, hf, offs, wgt);
    issue_plane(planesT, offs + 0, stage);
    calc_plane(1, cx, cy, cz, b, hf, offs, wgt);
    calc_plane(2, cx, cy, cz, b, hf, offs, wgt);

    float prod[16];
    half8 c0[4], c1[4];

    // ---- plane 0
    asm volatile("s_waitcnt vmcnt(0)" ::: "memory");
    __builtin_amdgcn_sched_barrier(0);
    read_slots(stage, tid, c0, c1);
    asm volatile("s_waitcnt lgkmcnt(0)" ::: "memory");
    __builtin_amdgcn_sched_barrier(0);
    issue_plane(planesT, offs + 4, stage);      // plane 1 in flight
    interp_plane(0, c0, c1, wgt, prod);         // hides under it

    // ---- plane 1
    asm volatile("s_waitcnt vmcnt(0)" ::: "memory");
    __builtin_amdgcn_sched_barrier(0);
    read_slots(stage, tid, c0, c1);
    asm volatile("s_waitcnt lgkmcnt(0)" ::: "memory");
    __builtin_amdgcn_sched_barrier(0);
    issue_plane(planesT, offs + 8, stage);      // plane 2 in flight
    interp_plane(1, c0, c1, wgt, prod);

    // ---- plane 2
    asm volatile("s_waitcnt vmcnt(0)" ::: "memory");
    __builtin_amdgcn_sched_barrier(0);
    read_slots(stage, tid, c0, c1);
    interp_plane(2, c0, c1, wgt, prod);         // compiler inserts lgkm wait

    half8 o0, o1;
    #pragma unroll
    for (int k = 0; k < 8; ++k) {
        o0[k] = (_Float16)(prod[k]     * 256.0f);
        o1[k] = (_Float16)(prod[8 + k] * 256.0f);
    }
    // feat write clobbers slots 0..2 — all slot reads retired above
    // (same LDS object -> compiler preserves read-before-write order).
    *(half8*)&wbase[p * FEAT_STRIDE + hf * 16 + 0] = o0;
    *(half8*)&wbase[p * FEAT_STRIDE + hf * 16 + 8] = o1;

    // a0 reads: same wave wrote these rows; lgkmcnt orders write->read.
    half8 a0[2];
    #pragma unroll
    for (int mt = 0; mt < 2; ++mt)
        a0[mt] = *(const half8*)&wbase[(mt * 16 + l15) * FEAT_STRIDE + quad * 8];

    // ================= layer 0 (h0 writes clobber feat region; WAR ordered
    // by lgkmcnt since a0 loads precede in program order) ===================
    #pragma unroll 1
    for (int nt = 0; nt < 8; ++nt) {
        const half8 bfr = w0r[nt];
        f32x4 acc[2];
        #pragma unroll
        for (int mt = 0; mt < 2; ++mt) {
            acc[mt] = (f32x4){0.f, 0.f, 0.f, 0.f};
            acc[mt] = __builtin_amdgcn_mfma_f32_16x16x32_f16(
                a0[mt], bfr, acc[mt], 0, 0, 0);
        }
        #pragma unroll
        for (int mt = 0; mt < 2; ++mt)
            #pragma unroll
            for (int r = 0; r < 4; ++r) {
                const float hval = fmaxf(acc[mt][r] + b0v[nt], 0.0f);
                wbase[(mt * 16 + quad * 4 + r) * H0_STRIDE + nt * 16 + l15]
                    = (_Float16)hval;
            }
    }

    // ================= layer 1 (+ fused layer-2 epilogue) ==================
    half8 a1[2][4];
    #pragma unroll
    for (int mt = 0; mt < 2; ++mt)
        #pragma unroll
        for (int ks = 0; ks < 4; ++ks)
            a1[mt][ks] = *(const half8*)
                &wbase[(mt * 16 + l15) * H0_STRIDE + ks * 32 + quad * 8];

    float part[2][4];
    #pragma unroll
    for (int mt = 0; mt < 2; ++mt)
        #pragma unroll
        for (int r = 0; r < 4; ++r) part[mt][r] = 0.0f;

    #pragma unroll 2
    for (int nt = 0; nt < 8; ++nt) {
        f32x4 acc[2];
        #pragma unroll
        for (int mt = 0; mt < 2; ++mt) acc[mt] = (f32x4){0.f, 0.f, 0.f, 0.f};
        #pragma unroll
        for (int ks = 0; ks < 4; ++ks) {
            const half8 bfr = *(const half8*)
                &w1h[(nt * 16 + l15) * 128 + ks * 32 + quad * 8];
            #pragma unroll
            for (int mt = 0; mt < 2; ++mt)
                acc[mt] = __builtin_amdgcn_mfma_f32_16x16x32_f16(
                    a1[mt][ks], bfr, acc[mt], 0, 0, 0);
        }
        #pragma unroll
        for (int mt = 0; mt < 2; ++mt)
            #pragma unroll
            for (int r = 0; r < 4; ++r)
                part[mt][r] = fmaf(w2s[nt], fmaxf(acc[mt][r] + b1v[nt], 0.0f),
                                   part[mt][r]);
    }

    // reduce across the 16 lanes (l15) of each quad-group
    #pragma unroll
    for (int mt = 0; mt < 2; ++mt)
        #pragma unroll
        for (int r = 0; r < 4; ++r) {
            float s = part[mt][r];
            s += __shfl_xor(s, 1);
            s += __shfl_xor(s, 2);
            s += __shfl_xor(s, 4);
            s += __shfl_xor(s, 8);
            part[mt][r] = s;
        }

    if (l15 == 0) {
        const int base = blockIdx.x * 32;
        #pragma unroll
        for (int mt = 0; mt < 2; ++mt)
            #pragma unroll
            for (int r = 0; r < 4; ++r)
                out[base + mt * 16 + quad * 4 + r] = part[mt][r] + bias2;
    }
}

// ---------------------------------------------------------------------------
// Fallback (ws too small): round-1 fused fp32 kernel on original layout.
// ---------------------------------------------------------------------------
__global__ __launch_bounds__(256) void fused_fallback(
    const float* __restrict__ planes, const float* __restrict__ coords,
    const float* __restrict__ w0, const float* __restrict__ b0,
    const float* __restrict__ w1, const float* __restrict__ b1,
    const float* __restrict__ w2, const float* __restrict__ b2,
    float* __restrict__ out)
{
    const int t = blockIdx.x * 256 + threadIdx.x;
    const int b = t >> 17;
    const float cx = coords[(size_t)t * 3 + 0];
    const float cy = coords[(size_t)t * 3 + 1];
    const float cz = coords[(size_t)t * 3 + 2];
    float feat[NCH];
    #pragma unroll
    for (int p = 0; p < 3; ++p) {
        const float u = (p == 0) ? cx : (p == 1) ? cy : cx;
        const float v = (p == 0) ? cy : cz;
        const float fx = (u + 1.0f) * 0.5f * (RES - 1);
        const float fy = (v + 1.0f) * 0.5f * (RES - 1);
        const float x0f = floorf(fx), y0f = floorf(fy);
        const float wx = fx - x0f, wy = fy - y0f;
        const int x0 = (int)x0f, y0 = (int)y0f;
        const bool vx1 = (x0 + 1) < RES, vy1 = (y0 + 1) < RES;
        const int x1 = vx1 ? x0 + 1 : RES - 1;
        const int y1 = vy1 ? y0 + 1 : RES - 1;
        float w00 = (1.0f - wx) * (1.0f - wy), w01 = wx * (1.0f - wy);
        float w10 = (1.0f - wx) * wy, w11 = wx * wy;
        if (!vx1) { w01 = 0.0f; w11 = 0.0f; }
        if (!vy1) { w10 = 0.0f; w11 = 0.0f; }
        const float* base = planes + (size_t)(b * 3 + p) * NCH * RES * RES;
        const float* p00 = base + (size_t)y0 * RES + x0;
        const float* p01 = base + (size_t)y0 * RES + x1;
        const float* p10 = base + (size_t)y1 * RES + x0;
        const float* p11 = base + (size_t)y1 * RES + x1;
        #pragma unroll
        for (int c = 0; c < NCH; ++c) {
            const size_t off = (size_t)c * RES * RES;
            float s = p00[off] * w00;
            s = fmaf(p01[off], w01, s);
            s = fmaf(p10[off], w10, s);
            s = fmaf(p11[off], w11, s);
            if (p == 0) feat[c] = s; else feat[c] *= s;
        }
    }
    float h0[128];
    #pragma unroll
    for (int g = 0; g < 128; ++g) {
        const float* wr = w0 + g * NCH;
        float aA = b0[g], aB = 0.0f;
        #pragma unroll
        for (int c = 0; c < NCH; c += 2) {
            aA = fmaf(wr[c], feat[c], aA);
            aB = fmaf(wr[c + 1], feat[c + 1], aB);
        }
        h0[g] = fmaxf(aA + aB, 0.0f);
    }
    float o = b2[0];
    for (int g = 0; g < 128; ++g) {
        const float* wr = w1 + g * 128;
        float aA = b1[g], aB = 0.0f, aC = 0.0f, aD = 0.0f;
        #pragma unroll
        for (int h = 0; h < 128; h += 4) {
            aA = fmaf(wr[h], h0[h], aA);
            aB = fmaf(wr[h + 1], h0[h + 1], aB);
            aC = fmaf(wr[h + 2], h0[h + 2], aC);
            aD = fmaf(wr[h + 3], h0[h + 3], aD);
        }
        o = fmaf(fmaxf((aA + aB) + (aC + aD), 0.0f), w2[g], o);
    }
    out[t] = o;
}

// ---------------------------------------------------------------------------
extern "C" void kernel_launch(void* const* d_in, const int* in_sizes, int n_in,
                              void* d_out, int out_size, void* d_ws, size_t ws_size,
                              hipStream_t stream)
{
    const float* trip   = (const float*)d_in[0];
    const float* coords = (const float*)d_in[1];
    const float* w0     = (const float*)d_in[2];
    const float* b0     = (const float*)d_in[3];
    const float* w1     = (const float*)d_in[4];
    const float* b1     = (const float*)d_in[5];
    const float* w2     = (const float*)d_in[6];
    const float* b2     = (const float*)d_in[7];
    float* out = (float*)d_out;

    const size_t planesTBytes = (size_t)NB * 3 * RES * RES * NCH * 2;   // 50331648
    const size_t w0hBytes = 128 * NCH * 2;                              // 8192
    const size_t w1hBytes = 128 * 128 * 2;                              // 32768
    const size_t needed = planesTBytes + w0hBytes + w1hBytes;

    if (ws_size >= needed) {
        _Float16* planesT = (_Float16*)d_ws;
        _Float16* w0h     = (_Float16*)((char*)d_ws + planesTBytes);
        _Float16* w1h     = (_Float16*)((char*)d_ws + planesTBytes + w0hBytes);

        transpose_prep_kernel<<<dim3(RES, NB * 3 + 1), 256, 0, stream>>>(
            trip, w0, w1, planesT, w0h, w1h);
        fused_kernel<<<(NB * NPT) / 32, 64, 0, stream>>>(
            planesT, coords, w0h, w1h, b0, b1, w2, b2, out);
    } else {
        fused_fallback<<<(NB * NPT) / 256, 256, 0, stream>>>(
            trip, coords, w0, b0, w1, b1, w2, b2, out);
    }
}

// Round 7
// 657.791 us; speedup vs baseline: 1.2135x; 1.0464x over previous
//
#include <hip/hip_runtime.h>
#include <hip/hip_bf16.h>
#include <cstddef>

#define RES 256
#define NCH 32
#define NPT 131072   // points per batch
#define NB  4

typedef _Float16 half8 __attribute__((ext_vector_type(8)));
typedef _Float16 half4 __attribute__((ext_vector_type(4)));
typedef float    f32x4 __attribute__((ext_vector_type(4)));

#define FEAT_STRIDE 40    // halves per feat row in R0-fused LDS (32+8 pad)
#define H0_STRIDE   136   // halves per h0 row (128+8 pad, 272B rows)
#define MLP_ITER    4     // 32-point chunks per mlp wave

// ---------------------------------------------------------------------------
// R18: phase-split. Six rounds showed the fused design is pinned by
// "sustained outstanding gathers/CU" (R0 10w x ~8 = 113.7us; R13 16w x ~4 =
// 126; R15 6w x 24 bursty = 128; R17 7w x 8 bursty = 543), and R14 (binned,
// L2-resident) proved it is NOT a bandwidth wall. The gather stage wants max
// TLP with no LDS/MFMA baggage; the MLP wants LDS+MFMA at modest occupancy.
// Split them:
//   sample_kernel: R0 phase-A verbatim, no LDS, no MFMA, feat -> workspace.
//                  launch_bounds(256,6) -> ~24 waves/CU (2.4x R0).
//   mlp_kernel:    R0 MFMA half, a0 fragments loaded DIRECT from feat
//                  (perfectly coalesced: a wave covers contiguous 1KB).
// Same values/ops/order as R0 -> bit-exact.
// ---------------------------------------------------------------------------

// ---------------------------------------------------------------------------
// Transpose + fp16 convert + weight prep (unchanged from R11).
// ---------------------------------------------------------------------------
__global__ __launch_bounds__(256) void transpose_prep_kernel(
    const float* __restrict__ in,
    const float* __restrict__ w0, const float* __restrict__ w1,
    _Float16* __restrict__ out,
    _Float16* __restrict__ w0h, _Float16* __restrict__ w1h)
{
    const int bp = blockIdx.y;                 // 0..12
    const int t  = threadIdx.x;

    if (bp == 12) {                            // weight-prep blocks
        const int i = blockIdx.x * 256 + t;
        if (i < 128 * NCH)  w0h[i] = (_Float16)(w0[i] * 16.0f);
        if (i < 128 * 128)  w1h[i] = (_Float16)w1[i];
        return;
    }

    __shared__ _Float16 tileh[NCH][RES + 8];   // 16.5 KB
    const int y = blockIdx.x;                  // 0..255

    const float4* src4 = (const float4*)(in + (size_t)bp * NCH * RES * RES);
    const int lane64 = t & 63;
    const int cq     = t >> 6;                 // 0..3
    #pragma unroll
    for (int i = 0; i < 8; ++i) {
        const int c = cq * 8 + i;
        const float4 v = src4[(size_t)c * (RES * RES / 4) + y * (RES / 4) + lane64];
        half4 h = { (_Float16)v.x, (_Float16)v.y, (_Float16)v.z, (_Float16)v.w };
        *(half4*)&tileh[c][lane64 * 4] = h;
    }
    __syncthreads();

    _Float16* dst = out + ((size_t)bp * RES * RES + (size_t)y * RES) * NCH;
    const int x = t;                           // texel 0..255
    #pragma unroll
    for (int cg = 0; cg < 4; ++cg) {
        half8 h;
        #pragma unroll
        for (int k = 0; k < 8; ++k)
            h[k] = tileh[cg * 8 + k][x];
        *(half8*)&dst[(size_t)x * NCH + cg * 8] = h;
    }
}

// ---------------------------------------------------------------------------
// Kernel S: bilinear sample only. 2 threads/point, register loads
// (compiler-scheduled — the R0-proven gather codegen), feat -> global.
// ---------------------------------------------------------------------------
__global__ __launch_bounds__(256, 6) void sample_kernel(
    const _Float16* __restrict__ planesT,   // [12][256][256][32] f16
    const float* __restrict__ coords,
    _Float16* __restrict__ featT)           // [524288][32] f16
{
    const int t  = blockIdx.x * 256 + threadIdx.x;
    const int p  = t >> 1;                  // global point id
    const int hf = t & 1;                   // channel half
    const int b  = p >> 17;                 // NPT = 2^17

    const float cx = coords[(size_t)p * 3 + 0];
    const float cy = coords[(size_t)p * 3 + 1];
    const float cz = coords[(size_t)p * 3 + 2];

    // ---- step 1: all 12 corner offsets + weights (identical to R0)
    int   offs[12];
    float wgt[12];
    #pragma unroll
    for (int pl = 0; pl < 3; ++pl) {
        const float u = (pl == 0) ? cx : (pl == 1) ? cy : cx;
        const float v = (pl == 0) ? cy : cz;

        const float fx = (u + 1.0f) * 0.5f * (RES - 1);
        const float fy = (v + 1.0f) * 0.5f * (RES - 1);
        const float x0f = floorf(fx), y0f = floorf(fy);
        const float wx = fx - x0f, wy = fy - y0f;
        const int x0 = (int)x0f, y0 = (int)y0f;
        const bool vx1 = (x0 + 1) < RES;
        const bool vy1 = (y0 + 1) < RES;
        const int x1 = vx1 ? x0 + 1 : RES - 1;
        const int y1 = vy1 ? y0 + 1 : RES - 1;

        float w00 = (1.0f - wx) * (1.0f - wy);
        float w01 = wx * (1.0f - wy);
        float w10 = (1.0f - wx) * wy;
        float w11 = wx * wy;
        if (!vx1) { w01 = 0.0f; w11 = 0.0f; }
        if (!vy1) { w10 = 0.0f; w11 = 0.0f; }

        // offset (halves) = ((b*3+pl)*65536 + y*256 + x)*32 + hf*16
        const int pbase = ((b * 3 + pl) << 21) + (hf << 4);
        offs[pl * 4 + 0] = pbase + (y0 << 13) + (x0 << 5);
        offs[pl * 4 + 1] = pbase + (y0 << 13) + (x1 << 5);
        offs[pl * 4 + 2] = pbase + (y1 << 13) + (x0 << 5);
        offs[pl * 4 + 3] = pbase + (y1 << 13) + (x1 << 5);
        wgt[pl * 4 + 0] = w00; wgt[pl * 4 + 1] = w01;
        wgt[pl * 4 + 2] = w10; wgt[pl * 4 + 3] = w11;
    }

    // ---- step 2: corner loads (unfenced; compiler schedules freely — R0)
    half8 L0[12], L1[12];
    #pragma unroll
    for (int i = 0; i < 12; ++i) {
        const _Float16* cp = planesT + (size_t)(unsigned)offs[i];
        L0[i] = *(const half8*)cp;
        L1[i] = *(const half8*)(cp + 8);
    }

    // ---- step 3: interpolate (identical FMA order to R0: bit-exact)
    float prod[16];
    #pragma unroll
    for (int pl = 0; pl < 3; ++pl) {
        #pragma unroll
        for (int k = 0; k < 8; ++k) {
            const float t0 =
                fmaf((float)L0[pl*4+3][k], wgt[pl*4+3],
                fmaf((float)L0[pl*4+2][k], wgt[pl*4+2],
                fmaf((float)L0[pl*4+1][k], wgt[pl*4+1],
                     (float)L0[pl*4+0][k] * wgt[pl*4+0])));
            const float t1 =
                fmaf((float)L1[pl*4+3][k], wgt[pl*4+3],
                fmaf((float)L1[pl*4+2][k], wgt[pl*4+2],
                fmaf((float)L1[pl*4+1][k], wgt[pl*4+1],
                     (float)L1[pl*4+0][k] * wgt[pl*4+0])));
            if (pl == 0) { prod[k] = t0;  prod[8 + k] = t1; }
            else         { prod[k] *= t0; prod[8 + k] *= t1; }
        }
    }

    half8 o0, o1;
    #pragma unroll
    for (int k = 0; k < 8; ++k) {
        o0[k] = (_Float16)(prod[k]     * 256.0f);
        o1[k] = (_Float16)(prod[8 + k] * 256.0f);
    }
    // 32B/thread, lane-pairs contiguous -> wave writes 2KB contiguous.
    *(half8*)&featT[(size_t)p * NCH + hf * 16 + 0] = o0;
    *(half8*)&featT[(size_t)p * NCH + hf * 16 + 8] = o1;
}

// ---------------------------------------------------------------------------
// Kernel M: MFMA MLP. One wave per block, MLP_ITER chunks of 32 points.
// a0 fragments load DIRECT from featT: for each mt the wave's 64 lanes read
// (quad*16 + l15*64) byte offsets = contiguous 1KB -> perfect coalescing.
// MFMA 16x16x32 f16 layouts (verified m89/m120 + rounds 3/4/6/7):
//   A: lane holds A[m=lane&15][k=quad*8+j]
//   B: lane holds B[k=quad*8+j][n=lane&15] = W[n][k] row-major 8-contig
//   C/D: col n = lane&15, row m = quad*4+reg
// ---------------------------------------------------------------------------
__global__ __launch_bounds__(64, 1) void mlp_kernel(
    const _Float16* __restrict__ featT,     // [524288][32] f16
    const _Float16* __restrict__ w0h,       // [128][32]  (x16)
    const _Float16* __restrict__ w1h,       // [128][128]
    const float* __restrict__ b0, const float* __restrict__ b1,
    const float* __restrict__ w2, const float* __restrict__ b2,
    float* __restrict__ out)
{
    __shared__ __align__(16) _Float16 h0s[32 * H0_STRIDE];   // 8704 B

    const int tid  = threadIdx.x;           // 0..63 (one wave)
    const int l15  = tid & 15;
    const int quad = tid >> 4;

    // hoisted per-lane weights/biases (amortized over MLP_ITER chunks)
    half8 w0r[8];
    float b0v[8], b1v[8], w2s[8];
    #pragma unroll
    for (int nt = 0; nt < 8; ++nt) {
        w0r[nt] = *(const half8*)&w0h[(nt * 16 + l15) * NCH + quad * 8];
        b0v[nt] = b0[nt * 16 + l15] * 4096.0f;
        b1v[nt] = b1[nt * 16 + l15] * 4096.0f;
        w2s[nt] = w2[nt * 16 + l15] * (1.0f / 4096.0f);
    }
    const float bias2 = b2[0];

    #pragma unroll 1
    for (int it = 0; it < MLP_ITER; ++it) {
        const int base = (blockIdx.x * MLP_ITER + it) * 32;

        // a0 fragments straight from global feat (coalesced 1KB/instr)
        half8 a0[2];
        #pragma unroll
        for (int mt = 0; mt < 2; ++mt)
            a0[mt] = *(const half8*)
                &featT[(size_t)(base + mt * 16 + l15) * NCH + quad * 8];

        // ---- layer 0 (h0s rewritten each chunk; same-wave lgkmcnt orders
        // prior a1 reads before these writes) ----
        #pragma unroll 1
        for (int nt = 0; nt < 8; ++nt) {
            const half8 bfr = w0r[nt];
            f32x4 acc[2];
            #pragma unroll
            for (int mt = 0; mt < 2; ++mt) {
                acc[mt] = (f32x4){0.f, 0.f, 0.f, 0.f};
                acc[mt] = __builtin_amdgcn_mfma_f32_16x16x32_f16(
                    a0[mt], bfr, acc[mt], 0, 0, 0);
            }
            #pragma unroll
            for (int mt = 0; mt < 2; ++mt)
                #pragma unroll
                for (int r = 0; r < 4; ++r) {
                    const float hval = fmaxf(acc[mt][r] + b0v[nt], 0.0f);
                    h0s[(mt * 16 + quad * 4 + r) * H0_STRIDE + nt * 16 + l15]
                        = (_Float16)hval;
                }
        }

        // ---- layer 1 (+ fused layer-2 epilogue) ----
        half8 a1[2][4];
        #pragma unroll
        for (int mt = 0; mt < 2; ++mt)
            #pragma unroll
            for (int ks = 0; ks < 4; ++ks)
                a1[mt][ks] = *(const half8*)
                    &h0s[(mt * 16 + l15) * H0_STRIDE + ks * 32 + quad * 8];

        float part[2][4];
        #pragma unroll
        for (int mt = 0; mt < 2; ++mt)
            #pragma unroll
            for (int r = 0; r < 4; ++r) part[mt][r] = 0.0f;

        #pragma unroll 2
        for (int nt = 0; nt < 8; ++nt) {
            f32x4 acc[2];
            #pragma unroll
            for (int mt = 0; mt < 2; ++mt) acc[mt] = (f32x4){0.f, 0.f, 0.f, 0.f};
            #pragma unroll
            for (int ks = 0; ks < 4; ++ks) {
                const half8 bfr = *(const half8*)
                    &w1h[(nt * 16 + l15) * 128 + ks * 32 + quad * 8];
                #pragma unroll
                for (int mt = 0; mt < 2; ++mt)
                    acc[mt] = __builtin_amdgcn_mfma_f32_16x16x32_f16(
                        a1[mt][ks], bfr, acc[mt], 0, 0, 0);
            }
            #pragma unroll
            for (int mt = 0; mt < 2; ++mt)
                #pragma unroll
                for (int r = 0; r < 4; ++r)
                    part[mt][r] = fmaf(w2s[nt],
                                       fmaxf(acc[mt][r] + b1v[nt], 0.0f),
                                       part[mt][r]);
        }

        #pragma unroll
        for (int mt = 0; mt < 2; ++mt)
            #pragma unroll
            for (int r = 0; r < 4; ++r) {
                float s = part[mt][r];
                s += __shfl_xor(s, 1);
                s += __shfl_xor(s, 2);
                s += __shfl_xor(s, 4);
                s += __shfl_xor(s, 8);
                part[mt][r] = s;
            }

        if (l15 == 0) {
            #pragma unroll
            for (int mt = 0; mt < 2; ++mt)
                #pragma unroll
                for (int r = 0; r < 4; ++r)
                    out[base + mt * 16 + quad * 4 + r] = part[mt][r] + bias2;
        }
    }
}

// ---------------------------------------------------------------------------
// Middle fallback (ws fits planesT but not featT): R0's fused kernel.
// ---------------------------------------------------------------------------
__global__ __launch_bounds__(64, 1) void fused_r0(
    const _Float16* __restrict__ planesT,
    const float* __restrict__ coords,
    const _Float16* __restrict__ w0h,
    const _Float16* __restrict__ w1h,
    const float* __restrict__ b0, const float* __restrict__ b1,
    const float* __restrict__ w2, const float* __restrict__ b2,
    float* __restrict__ out)
{
    __shared__ __align__(16) _Float16 wbase[32 * H0_STRIDE];

    const int tid  = threadIdx.x;
    const int l15  = tid & 15;
    const int quad = tid >> 4;

    {
        const int p  = tid >> 1;
        const int hf = tid & 1;
        const int gp = blockIdx.x * 32 + p;
        const int b  = gp >> 17;
        const float cx = coords[(size_t)gp * 3 + 0];
        const float cy = coords[(size_t)gp * 3 + 1];
        const float cz = coords[(size_t)gp * 3 + 2];

        int   offs[12];
        float wgt[12];
        #pragma unroll
        for (int pl = 0; pl < 3; ++pl) {
            const float u = (pl == 0) ? cx : (pl == 1) ? cy : cx;
            const float v = (pl == 0) ? cy : cz;
            const float fx = (u + 1.0f) * 0.5f * (RES - 1);
            const float fy = (v + 1.0f) * 0.5f * (RES - 1);
            const float x0f = floorf(fx), y0f = floorf(fy);
            const float wx = fx - x0f, wy = fy - y0f;
            const int x0 = (int)x0f, y0 = (int)y0f;
            const bool vx1 = (x0 + 1) < RES;
            const bool vy1 = (y0 + 1) < RES;
            const int x1 = vx1 ? x0 + 1 : RES - 1;
            const int y1 = vy1 ? y0 + 1 : RES - 1;
            float w00 = (1.0f - wx) * (1.0f - wy);
            float w01 = wx * (1.0f - wy);
            float w10 = (1.0f - wx) * wy;
            float w11 = wx * wy;
            if (!vx1) { w01 = 0.0f; w11 = 0.0f; }
            if (!vy1) { w10 = 0.0f; w11 = 0.0f; }
            const int pbase = ((b * 3 + pl) << 21) + (hf << 4);
            offs[pl * 4 + 0] = pbase + (y0 << 13) + (x0 << 5);
            offs[pl * 4 + 1] = pbase + (y0 << 13) + (x1 << 5);
            offs[pl * 4 + 2] = pbase + (y1 << 13) + (x0 << 5);
            offs[pl * 4 + 3] = pbase + (y1 << 13) + (x1 << 5);
            wgt[pl * 4 + 0] = w00; wgt[pl * 4 + 1] = w01;
            wgt[pl * 4 + 2] = w10; wgt[pl * 4 + 3] = w11;
        }

        half8 L0[12], L1[12];
        #pragma unroll
        for (int i = 0; i < 12; ++i) {
            const _Float16* cp = planesT + (size_t)(unsigned)offs[i];
            L0[i] = *(const half8*)cp;
            L1[i] = *(const half8*)(cp + 8);
        }

        float prod[16];
        #pragma unroll
        for (int pl = 0; pl < 3; ++pl) {
            #pragma unroll
            for (int k = 0; k < 8; ++k) {
                const float t0 =
                    fmaf((float)L0[pl*4+3][k], wgt[pl*4+3],
                    fmaf((float)L0[pl*4+2][k], wgt[pl*4+2],
                    fmaf((float)L0[pl*4+1][k], wgt[pl*4+1],
                         (float)L0[pl*4+0][k] * wgt[pl*4+0])));
                const float t1 =
                    fmaf((float)L1[pl*4+3][k], wgt[pl*4+3],
                    fmaf((float)L1[pl*4+2][k], wgt[pl*4+2],
                    fmaf((float)L1[pl*4+1][k], wgt[pl*4+1],
                         (float)L1[pl*4+0][k] * wgt[pl*4+0])));
                if (pl == 0) { prod[k] = t0;  prod[8 + k] = t1; }
                else         { prod[k] *= t0; prod[8 + k] *= t1; }
            }
        }

        half8 o0, o1;
        #pragma unroll
        for (int k = 0; k < 8; ++k) {
            o0[k] = (_Float16)(prod[k]     * 256.0f);
            o1[k] = (_Float16)(prod[8 + k] * 256.0f);
        }
        *(half8*)&wbase[p * FEAT_STRIDE + hf * 16 + 0] = o0;
        *(half8*)&wbase[p * FEAT_STRIDE + hf * 16 + 8] = o1;
    }

    half8 a0[2];
    #pragma unroll
    for (int mt = 0; mt < 2; ++mt)
        a0[mt] = *(const half8*)&wbase[(mt * 16 + l15) * FEAT_STRIDE + quad * 8];

    float b0v[8], b1v[8], w2s[8];
    #pragma unroll
    for (int nt = 0; nt < 8; ++nt) {
        b0v[nt] = b0[nt * 16 + l15] * 4096.0f;
        b1v[nt] = b1[nt * 16 + l15] * 4096.0f;
        w2s[nt] = w2[nt * 16 + l15] * (1.0f / 4096.0f);
    }

    #pragma unroll 1
    for (int nt = 0; nt < 8; ++nt) {
        const half8 bfr = *(const half8*)&w0h[(nt * 16 + l15) * NCH + quad * 8];
        f32x4 acc[2];
        #pragma unroll
        for (int mt = 0; mt < 2; ++mt) {
            acc[mt] = (f32x4){0.f, 0.f, 0.f, 0.f};
            acc[mt] = __builtin_amdgcn_mfma_f32_16x16x32_f16(
                a0[mt], bfr, acc[mt], 0, 0, 0);
        }
        #pragma unroll
        for (int mt = 0; mt < 2; ++mt)
            #pragma unroll
            for (int r = 0; r < 4; ++r) {
                const float hval = fmaxf(acc[mt][r] + b0v[nt], 0.0f);
                wbase[(mt * 16 + quad * 4 + r) * H0_STRIDE + nt * 16 + l15]
                    = (_Float16)hval;
            }
    }

    half8 a1[2][4];
    #pragma unroll
    for (int mt = 0; mt < 2; ++mt)
        #pragma unroll
        for (int ks = 0; ks < 4; ++ks)
            a1[mt][ks] = *(const half8*)
                &wbase[(mt * 16 + l15) * H0_STRIDE + ks * 32 + quad * 8];

    float part[2][4];
    #pragma unroll
    for (int mt = 0; mt < 2; ++mt)
        #pragma unroll
        for (int r = 0; r < 4; ++r) part[mt][r] = 0.0f;

    #pragma unroll 2
    for (int nt = 0; nt < 8; ++nt) {
        f32x4 acc[2];
        #pragma unroll
        for (int mt = 0; mt < 2; ++mt) acc[mt] = (f32x4){0.f, 0.f, 0.f, 0.f};
        #pragma unroll
        for (int ks = 0; ks < 4; ++ks) {
            const half8 bfr = *(const half8*)
                &w1h[(nt * 16 + l15) * 128 + ks * 32 + quad * 8];
            #pragma unroll
            for (int mt = 0; mt < 2; ++mt)
                acc[mt] = __builtin_amdgcn_mfma_f32_16x16x32_f16(
                    a1[mt][ks], bfr, acc[mt], 0, 0, 0);
        }
        #pragma unroll
        for (int mt = 0; mt < 2; ++mt)
            #pragma unroll
            for (int r = 0; r < 4; ++r)
                part[mt][r] = fmaf(w2s[nt], fmaxf(acc[mt][r] + b1v[nt], 0.0f),
                                   part[mt][r]);
    }

    #pragma unroll
    for (int mt = 0; mt < 2; ++mt)
        #pragma unroll
        for (int r = 0; r < 4; ++r) {
            float s = part[mt][r];
            s += __shfl_xor(s, 1);
            s += __shfl_xor(s, 2);
            s += __shfl_xor(s, 4);
            s += __shfl_xor(s, 8);
            part[mt][r] = s;
        }

    if (l15 == 0) {
        const float bias2 = b2[0];
        const int base = blockIdx.x * 32;
        #pragma unroll
        for (int mt = 0; mt < 2; ++mt)
            #pragma unroll
            for (int r = 0; r < 4; ++r)
                out[base + mt * 16 + quad * 4 + r] = part[mt][r] + bias2;
    }
}

// ---------------------------------------------------------------------------
// Fallback (ws too small): round-1 fused fp32 kernel on original layout.
// ---------------------------------------------------------------------------
__global__ __launch_bounds__(256) void fused_fallback(
    const float* __restrict__ planes, const float* __restrict__ coords,
    const float* __restrict__ w0, const float* __restrict__ b0,
    const float* __restrict__ w1, const float* __restrict__ b1,
    const float* __restrict__ w2, const float* __restrict__ b2,
    float* __restrict__ out)
{
    const int t = blockIdx.x * 256 + threadIdx.x;
    const int b = t >> 17;
    const float cx = coords[(size_t)t * 3 + 0];
    const float cy = coords[(size_t)t * 3 + 1];
    const float cz = coords[(size_t)t * 3 + 2];
    float feat[NCH];
    #pragma unroll
    for (int p = 0; p < 3; ++p) {
        const float u = (p == 0) ? cx : (p == 1) ? cy : cx;
        const float v = (p == 0) ? cy : cz;
        const float fx = (u + 1.0f) * 0.5f * (RES - 1);
        const float fy = (v + 1.0f) * 0.5f * (RES - 1);
        const float x0f = floorf(fx), y0f = floorf(fy);
        const float wx = fx - x0f, wy = fy - y0f;
        const int x0 = (int)x0f, y0 = (int)y0f;
        const bool vx1 = (x0 + 1) < RES, vy1 = (y0 + 1) < RES;
        const int x1 = vx1 ? x0 + 1 : RES - 1;
        const int y1 = vy1 ? y0 + 1 : RES - 1;
        float w00 = (1.0f - wx) * (1.0f - wy), w01 = wx * (1.0f - wy);
        float w10 = (1.0f - wx) * wy, w11 = wx * wy;
        if (!vx1) { w01 = 0.0f; w11 = 0.0f; }
        if (!vy1) { w10 = 0.0f; w11 = 0.0f; }
        const float* base = planes + (size_t)(b * 3 + p) * NCH * RES * RES;
        const float* p00 = base + (size_t)y0 * RES + x0;
        const float* p01 = base + (size_t)y0 * RES + x1;
        const float* p10 = base + (size_t)y1 * RES + x0;
        const float* p11 = base + (size_t)y1 * RES + x1;
        #pragma unroll
        for (int c = 0; c < NCH; ++c) {
            const size_t off = (size_t)c * RES * RES;
            float s = p00[off] * w00;
            s = fmaf(p01[off], w01, s);
            s = fmaf(p10[off], w10, s);
            s = fmaf(p11[off], w11, s);
            if (p == 0) feat[c] = s; else feat[c] *= s;
        }
    }
    float h0[128];
    #pragma unroll
    for (int g = 0; g < 128; ++g) {
        const float* wr = w0 + g * NCH;
        float aA = b0[g], aB = 0.0f;
        #pragma unroll
        for (int c = 0; c < NCH; c += 2) {
            aA = fmaf(wr[c], feat[c], aA);
            aB = fmaf(wr[c + 1], feat[c + 1], aB);
        }
        h0[g] = fmaxf(aA + aB, 0.0f);
    }
    float o = b2[0];
    for (int g = 0; g < 128; ++g) {
        const float* wr = w1 + g * 128;
        float aA = b1[g], aB = 0.0f, aC = 0.0f, aD = 0.0f;
        #pragma unroll
        for (int h = 0; h < 128; h += 4) {
            aA = fmaf(wr[h], h0[h], aA);
            aB = fmaf(wr[h + 1], h0[h + 1], aB);
            aC = fmaf(wr[h + 2], h0[h + 2], aC);
            aD = fmaf(wr[h + 3], h0[h + 3], aD);
        }
        o = fmaf(fmaxf((aA + aB) + (aC + aD), 0.0f), w2[g], o);
    }
    out[t] = o;
}

// ---------------------------------------------------------------------------
extern "C" void kernel_launch(void* const* d_in, const int* in_sizes, int n_in,
                              void* d_out, int out_size, void* d_ws, size_t ws_size,
                              hipStream_t stream)
{
    const float* trip   = (const float*)d_in[0];
    const float* coords = (const float*)d_in[1];
    const float* w0     = (const float*)d_in[2];
    const float* b0     = (const float*)d_in[3];
    const float* w1     = (const float*)d_in[4];
    const float* b1     = (const float*)d_in[5];
    const float* w2     = (const float*)d_in[6];
    const float* b2     = (const float*)d_in[7];
    float* out = (float*)d_out;

    const size_t planesTBytes = (size_t)NB * 3 * RES * RES * NCH * 2;   // 50331648
    const size_t w0hBytes  = 128 * NCH * 2;                             // 8192
    const size_t w1hBytes  = 128 * 128 * 2;                             // 32768
    const size_t featBytes = (size_t)NB * NPT * NCH * 2;                // 33554432
    const size_t needed  = planesTBytes + w0hBytes + w1hBytes;
    const size_t needed2 = needed + featBytes;

    if (ws_size >= needed2) {
        char* ws = (char*)d_ws;
        _Float16* planesT = (_Float16*)ws;
        _Float16* w0h     = (_Float16*)(ws + planesTBytes);
        _Float16* w1h     = (_Float16*)(ws + planesTBytes + w0hBytes);
        _Float16* featT   = (_Float16*)(ws + needed);

        transpose_prep_kernel<<<dim3(RES, NB * 3 + 1), 256, 0, stream>>>(
            trip, w0, w1, planesT, w0h, w1h);
        sample_kernel<<<(NB * NPT * 2) / 256, 256, 0, stream>>>(
            planesT, coords, featT);
        mlp_kernel<<<(NB * NPT) / (32 * MLP_ITER), 64, 0, stream>>>(
            featT, w0h, w1h, b0, b1, w2, b2, out);
    } else if (ws_size >= needed) {
        _Float16* planesT = (_Float16*)d_ws;
        _Float16* w0h     = (_Float16*)((char*)d_ws + planesTBytes);
        _Float16* w1h     = (_Float16*)((char*)d_ws + planesTBytes + w0hBytes);
        transpose_prep_kernel<<<dim3(RES, NB * 3 + 1), 256, 0, stream>>>(
            trip, w0, w1, planesT, w0h, w1h);
        fused_r0<<<(NB * NPT) / 32, 64, 0, stream>>>(
            planesT, coords, w0h, w1h, b0, b1, w2, b2, out);
    } else {
        fused_fallback<<<(NB * NPT) / 256, 256, 0, stream>>>(
            trip, coords, w0, b0, w1, b1, w2, b2, out);
    }
}

// Round 8
// 274.277 us; speedup vs baseline: 2.9103x; 2.3983x over previous
//
#include <hip/hip_runtime.h>
#include <hip/hip_bf16.h>
#include <cstddef>

#define RES 256
#define NCH 32
#define NPT 131072   // points per batch
#define NB  4

typedef _Float16 half8 __attribute__((ext_vector_type(8)));
typedef _Float16 half4 __attribute__((ext_vector_type(4)));
typedef float    f32x4 __attribute__((ext_vector_type(4)));

#define FEAT_STRIDE 40    // halves per feat row (32+8 pad, 80B rows)
#define H0_STRIDE   136   // halves per h0 row (128+8 pad, 272B rows)

// ---------------------------------------------------------------------------
// R19: quad-merged gathers. R0's 2-lane/point scheme fetched each corner's
// 64 contiguous bytes as 4 discontiguous 16B lane-requests across 2 instrs
// (no TA quad-merge possible) = 48 requests/point, 96 data-VGPRs/thread
// (why the scheduler always sank the batch, R10-R13). Remap to 4 lanes/point
// (lane q owns channels q*8..q*8+7): corner i's load has lanes 4p..4p+3
// covering ONE aligned 64B line -> guaranteed quad-coalesce: 12 line-requests
// /point (4x fewer), 48 data-VGPRs/thread. Two 16-point rounds; all 24 loads
// issued before a single keep-alive wall (asm operand wall — sched_barrier
// was provably defeated in R10/R11) -> one latency exposure.
// Per-channel FMA chains identical to R0 -> bit-exact. MLP half R0 verbatim.
// ---------------------------------------------------------------------------

// ---------------------------------------------------------------------------
// Transpose + fp16 convert + weight prep (unchanged from R11).
// ---------------------------------------------------------------------------
__global__ __launch_bounds__(256) void transpose_prep_kernel(
    const float* __restrict__ in,
    const float* __restrict__ w0, const float* __restrict__ w1,
    _Float16* __restrict__ out,
    _Float16* __restrict__ w0h, _Float16* __restrict__ w1h)
{
    const int bp = blockIdx.y;                 // 0..12
    const int t  = threadIdx.x;

    if (bp == 12) {                            // weight-prep blocks
        const int i = blockIdx.x * 256 + t;
        if (i < 128 * NCH)  w0h[i] = (_Float16)(w0[i] * 16.0f);
        if (i < 128 * 128)  w1h[i] = (_Float16)w1[i];
        return;
    }

    __shared__ _Float16 tileh[NCH][RES + 8];   // 16.5 KB
    const int y = blockIdx.x;                  // 0..255

    const float4* src4 = (const float4*)(in + (size_t)bp * NCH * RES * RES);
    const int lane64 = t & 63;
    const int cq     = t >> 6;                 // 0..3
    #pragma unroll
    for (int i = 0; i < 8; ++i) {
        const int c = cq * 8 + i;
        const float4 v = src4[(size_t)c * (RES * RES / 4) + y * (RES / 4) + lane64];
        half4 h = { (_Float16)v.x, (_Float16)v.y, (_Float16)v.z, (_Float16)v.w };
        *(half4*)&tileh[c][lane64 * 4] = h;
    }
    __syncthreads();

    _Float16* dst = out + ((size_t)bp * RES * RES + (size_t)y * RES) * NCH;
    const int x = t;                           // texel 0..255
    #pragma unroll
    for (int cg = 0; cg < 4; ++cg) {
        half8 h;
        #pragma unroll
        for (int k = 0; k < 8; ++k)
            h[k] = tileh[cg * 8 + k][x];
        *(half8*)&dst[(size_t)x * NCH + cg * 8] = h;
    }
}

// ---------------------------------------------------------------------------
// Per-point corner offsets/weights. offs holds TEXEL base (halves) + q*8.
// ---------------------------------------------------------------------------
__device__ __forceinline__ void calc_corners_q(
    const float* __restrict__ coords, int gp, int q,
    int* __restrict__ offs, float* __restrict__ wgt)
{
    const int b = gp >> 17;                    // NPT = 2^17
    const float cx = coords[(size_t)gp * 3 + 0];
    const float cy = coords[(size_t)gp * 3 + 1];
    const float cz = coords[(size_t)gp * 3 + 2];

    #pragma unroll
    for (int pl = 0; pl < 3; ++pl) {
        const float u = (pl == 0) ? cx : (pl == 1) ? cy : cx;
        const float v = (pl == 0) ? cy : cz;

        const float fx = (u + 1.0f) * 0.5f * (RES - 1);
        const float fy = (v + 1.0f) * 0.5f * (RES - 1);
        const float x0f = floorf(fx), y0f = floorf(fy);
        const float wx = fx - x0f, wy = fy - y0f;
        const int x0 = (int)x0f, y0 = (int)y0f;
        const bool vx1 = (x0 + 1) < RES;
        const bool vy1 = (y0 + 1) < RES;
        const int x1 = vx1 ? x0 + 1 : RES - 1;
        const int y1 = vy1 ? y0 + 1 : RES - 1;

        float w00 = (1.0f - wx) * (1.0f - wy);
        float w01 = wx * (1.0f - wy);
        float w10 = (1.0f - wx) * wy;
        float w11 = wx * wy;
        if (!vx1) { w01 = 0.0f; w11 = 0.0f; }
        if (!vy1) { w10 = 0.0f; w11 = 0.0f; }

        // offset (halves) = ((b*3+pl)*65536 + y*256 + x)*32 + q*8
        const int pbase = ((b * 3 + pl) << 21) + (q << 3);
        offs[pl * 4 + 0] = pbase + (y0 << 13) + (x0 << 5);
        offs[pl * 4 + 1] = pbase + (y0 << 13) + (x1 << 5);
        offs[pl * 4 + 2] = pbase + (y1 << 13) + (x0 << 5);
        offs[pl * 4 + 3] = pbase + (y1 << 13) + (x1 << 5);
        wgt[pl * 4 + 0] = w00; wgt[pl * 4 + 1] = w01;
        wgt[pl * 4 + 2] = w10; wgt[pl * 4 + 3] = w11;
    }
}

// ---------------------------------------------------------------------------
// Fused sample + MFMA MLP, one wave per block, zero barriers.
// MFMA 16x16x32 f16 layouts (verified m89/m120 + rounds 3/4/6/7):
//   A: lane holds A[m=lane&15][k=quad*8+j]
//   B: lane holds B[k=quad*8+j][n=lane&15] = W[n][k] row-major 8-contig
//   C/D: col n = lane&15, row m = quad*4+reg
// ---------------------------------------------------------------------------
__global__ __launch_bounds__(64, 1) void fused_kernel(
    const _Float16* __restrict__ planesT,   // [12][256][256][32] f16
    const float* __restrict__ coords,
    const _Float16* __restrict__ w0h,       // [128][32]  (x16)
    const _Float16* __restrict__ w1h,       // [128][128]
    const float* __restrict__ b0, const float* __restrict__ b1,
    const float* __restrict__ w2, const float* __restrict__ b2,
    float* __restrict__ out)
{
    __shared__ __align__(16) _Float16 wbase[32 * H0_STRIDE];   // 8704 B

    const int tid  = threadIdx.x;           // 0..63 (one wave)
    const int l15  = tid & 15;
    const int quad = tid >> 4;

    // ================= phase A: bilinear sample, 4 threads/point ===========
    {
        const int q  = tid & 3;             // 16B channel-quarter
        const int pr = tid >> 2;            // point-in-round 0..15

        int   offs0[12], offs1[12];
        float wgt0[12], wgt1[12];
        calc_corners_q(coords, blockIdx.x * 32 + pr,      q, offs0, wgt0);
        // round-0 loads: lanes 4p..4p+3 cover one aligned 64B line per corner
        half8 C0[12];
        #pragma unroll
        for (int i = 0; i < 12; ++i)
            C0[i] = *(const half8*)(planesT + (size_t)(unsigned)offs0[i]);

        calc_corners_q(coords, blockIdx.x * 32 + 16 + pr, q, offs1, wgt1);
        half8 C1[12];
        #pragma unroll
        for (int i = 0; i < 12; ++i)
            C1[i] = *(const half8*)(planesT + (size_t)(unsigned)offs1[i]);

        // keep-alive wall: all 24 loads must be issued and completed here —
        // the values are asm operands, so the scheduler cannot sink the
        // loads into the FMA chains (the R10-R13 serialization pathology).
        asm volatile("" ::
            "v"(C0[0]), "v"(C0[1]), "v"(C0[2]),  "v"(C0[3]),
            "v"(C0[4]), "v"(C0[5]), "v"(C0[6]),  "v"(C0[7]),
            "v"(C0[8]), "v"(C0[9]), "v"(C0[10]), "v"(C0[11]));
        asm volatile("" ::
            "v"(C1[0]), "v"(C1[1]), "v"(C1[2]),  "v"(C1[3]),
            "v"(C1[4]), "v"(C1[5]), "v"(C1[6]),  "v"(C1[7]),
            "v"(C1[8]), "v"(C1[9]), "v"(C1[10]), "v"(C1[11]));

        // ---- interpolate: identical per-channel FMA chains to R0-R18
        // (channel c = q*8+k; old t0/t1 chains map 1:1 onto q) -> bit-exact.
        float prod0[8], prod1[8];
        #pragma unroll
        for (int pl = 0; pl < 3; ++pl) {
            #pragma unroll
            for (int k = 0; k < 8; ++k) {
                const float t0 =
                    fmaf((float)C0[pl*4+3][k], wgt0[pl*4+3],
                    fmaf((float)C0[pl*4+2][k], wgt0[pl*4+2],
                    fmaf((float)C0[pl*4+1][k], wgt0[pl*4+1],
                         (float)C0[pl*4+0][k] * wgt0[pl*4+0])));
                const float t1 =
                    fmaf((float)C1[pl*4+3][k], wgt1[pl*4+3],
                    fmaf((float)C1[pl*4+2][k], wgt1[pl*4+2],
                    fmaf((float)C1[pl*4+1][k], wgt1[pl*4+1],
                         (float)C1[pl*4+0][k] * wgt1[pl*4+0])));
                if (pl == 0) { prod0[k] = t0;  prod1[k] = t1; }
                else         { prod0[k] *= t0; prod1[k] *= t1; }
            }
        }

        half8 o0, o1;
        #pragma unroll
        for (int k = 0; k < 8; ++k) {
            o0[k] = (_Float16)(prod0[k] * 256.0f);
            o1[k] = (_Float16)(prod1[k] * 256.0f);
        }
        *(half8*)&wbase[pr        * FEAT_STRIDE + q * 8] = o0;
        *(half8*)&wbase[(16 + pr) * FEAT_STRIDE + q * 8] = o1;
    }

    // a0 reads: same wave wrote these rows; lgkmcnt orders write->read.
    half8 a0[2];
    #pragma unroll
    for (int mt = 0; mt < 2; ++mt)
        a0[mt] = *(const half8*)&wbase[(mt * 16 + l15) * FEAT_STRIDE + quad * 8];

    // per-lane bias/weight scalars
    float b0v[8], b1v[8], w2s[8];
    #pragma unroll
    for (int nt = 0; nt < 8; ++nt) {
        b0v[nt] = b0[nt * 16 + l15] * 4096.0f;
        b1v[nt] = b1[nt * 16 + l15] * 4096.0f;
        w2s[nt] = w2[nt * 16 + l15] * (1.0f / 4096.0f);
    }

    // ================= layer 0 (h0 writes clobber feat region; WAR ordered
    // by lgkmcnt since a0 loads precede in program order) ===================
    #pragma unroll 1
    for (int nt = 0; nt < 8; ++nt) {
        const half8 bfr = *(const half8*)&w0h[(nt * 16 + l15) * NCH + quad * 8];
        f32x4 acc[2];
        #pragma unroll
        for (int mt = 0; mt < 2; ++mt) {
            acc[mt] = (f32x4){0.f, 0.f, 0.f, 0.f};
            acc[mt] = __builtin_amdgcn_mfma_f32_16x16x32_f16(
                a0[mt], bfr, acc[mt], 0, 0, 0);
        }
        #pragma unroll
        for (int mt = 0; mt < 2; ++mt)
            #pragma unroll
            for (int r = 0; r < 4; ++r) {
                const float hval = fmaxf(acc[mt][r] + b0v[nt], 0.0f);
                wbase[(mt * 16 + quad * 4 + r) * H0_STRIDE + nt * 16 + l15]
                    = (_Float16)hval;
            }
    }

    // ================= layer 1 (+ fused layer-2 epilogue) ==================
    half8 a1[2][4];
    #pragma unroll
    for (int mt = 0; mt < 2; ++mt)
        #pragma unroll
        for (int ks = 0; ks < 4; ++ks)
            a1[mt][ks] = *(const half8*)
                &wbase[(mt * 16 + l15) * H0_STRIDE + ks * 32 + quad * 8];

    float part[2][4];
    #pragma unroll
    for (int mt = 0; mt < 2; ++mt)
        #pragma unroll
        for (int r = 0; r < 4; ++r) part[mt][r] = 0.0f;

    #pragma unroll 2
    for (int nt = 0; nt < 8; ++nt) {
        f32x4 acc[2];
        #pragma unroll
        for (int mt = 0; mt < 2; ++mt) acc[mt] = (f32x4){0.f, 0.f, 0.f, 0.f};
        #pragma unroll
        for (int ks = 0; ks < 4; ++ks) {
            const half8 bfr = *(const half8*)
                &w1h[(nt * 16 + l15) * 128 + ks * 32 + quad * 8];
            #pragma unroll
            for (int mt = 0; mt < 2; ++mt)
                acc[mt] = __builtin_amdgcn_mfma_f32_16x16x32_f16(
                    a1[mt][ks], bfr, acc[mt], 0, 0, 0);
        }
        #pragma unroll
        for (int mt = 0; mt < 2; ++mt)
            #pragma unroll
            for (int r = 0; r < 4; ++r)
                part[mt][r] = fmaf(w2s[nt], fmaxf(acc[mt][r] + b1v[nt], 0.0f),
                                   part[mt][r]);
    }

    // reduce across the 16 lanes (l15) of each quad-group
    #pragma unroll
    for (int mt = 0; mt < 2; ++mt)
        #pragma unroll
        for (int r = 0; r < 4; ++r) {
            float s = part[mt][r];
            s += __shfl_xor(s, 1);
            s += __shfl_xor(s, 2);
            s += __shfl_xor(s, 4);
            s += __shfl_xor(s, 8);
            part[mt][r] = s;
        }

    if (l15 == 0) {
        const float bias2 = b2[0];
        const int base = blockIdx.x * 32;
        #pragma unroll
        for (int mt = 0; mt < 2; ++mt)
            #pragma unroll
            for (int r = 0; r < 4; ++r)
                out[base + mt * 16 + quad * 4 + r] = part[mt][r] + bias2;
    }
}

// ---------------------------------------------------------------------------
// Fallback (ws too small): round-1 fused fp32 kernel on original layout.
// ---------------------------------------------------------------------------
__global__ __launch_bounds__(256) void fused_fallback(
    const float* __restrict__ planes, const float* __restrict__ coords,
    const float* __restrict__ w0, const float* __restrict__ b0,
    const float* __restrict__ w1, const float* __restrict__ b1,
    const float* __restrict__ w2, const float* __restrict__ b2,
    float* __restrict__ out)
{
    const int t = blockIdx.x * 256 + threadIdx.x;
    const int b = t >> 17;
    const float cx = coords[(size_t)t * 3 + 0];
    const float cy = coords[(size_t)t * 3 + 1];
    const float cz = coords[(size_t)t * 3 + 2];
    float feat[NCH];
    #pragma unroll
    for (int p = 0; p < 3; ++p) {
        const float u = (p == 0) ? cx : (p == 1) ? cy : cx;
        const float v = (p == 0) ? cy : cz;
        const float fx = (u + 1.0f) * 0.5f * (RES - 1);
        const float fy = (v + 1.0f) * 0.5f * (RES - 1);
        const float x0f = floorf(fx), y0f = floorf(fy);
        const float wx = fx - x0f, wy = fy - y0f;
        const int x0 = (int)x0f, y0 = (int)y0f;
        const bool vx1 = (x0 + 1) < RES, vy1 = (y0 + 1) < RES;
        const int x1 = vx1 ? x0 + 1 : RES - 1;
        const int y1 = vy1 ? y0 + 1 : RES - 1;
        float w00 = (1.0f - wx) * (1.0f - wy), w01 = wx * (1.0f - wy);
        float w10 = (1.0f - wx) * wy, w11 = wx * wy;
        if (!vx1) { w01 = 0.0f; w11 = 0.0f; }
        if (!vy1) { w10 = 0.0f; w11 = 0.0f; }
        const float* base = planes + (size_t)(b * 3 + p) * NCH * RES * RES;
        const float* p00 = base + (size_t)y0 * RES + x0;
        const float* p01 = base + (size_t)y0 * RES + x1;
        const float* p10 = base + (size_t)y1 * RES + x0;
        const float* p11 = base + (size_t)y1 * RES + x1;
        #pragma unroll
        for (int c = 0; c < NCH; ++c) {
            const size_t off = (size_t)c * RES * RES;
            float s = p00[off] * w00;
            s = fmaf(p01[off], w01, s);
            s = fmaf(p10[off], w10, s);
            s = fmaf(p11[off], w11, s);
            if (p == 0) feat[c] = s; else feat[c] *= s;
        }
    }
    float h0[128];
    #pragma unroll
    for (int g = 0; g < 128; ++g) {
        const float* wr = w0 + g * NCH;
        float aA = b0[g], aB = 0.0f;
        #pragma unroll
        for (int c = 0; c < NCH; c += 2) {
            aA = fmaf(wr[c], feat[c], aA);
            aB = fmaf(wr[c + 1], feat[c + 1], aB);
        }
        h0[g] = fmaxf(aA + aB, 0.0f);
    }
    float o = b2[0];
    for (int g = 0; g < 128; ++g) {
        const float* wr = w1 + g * 128;
        float aA = b1[g], aB = 0.0f, aC = 0.0f, aD = 0.0f;
        #pragma unroll
        for (int h = 0; h < 128; h += 4) {
            aA = fmaf(wr[h], h0[h], aA);
            aB = fmaf(wr[h + 1], h0[h + 1], aB);
            aC = fmaf(wr[h + 2], h0[h + 2], aC);
            aD = fmaf(wr[h + 3], h0[h + 3], aD);
        }
        o = fmaf(fmaxf((aA + aB) + (aC + aD), 0.0f), w2[g], o);
    }
    out[t] = o;
}

// ---------------------------------------------------------------------------
extern "C" void kernel_launch(void* const* d_in, const int* in_sizes, int n_in,
                              void* d_out, int out_size, void* d_ws, size_t ws_size,
                              hipStream_t stream)
{
    const float* trip   = (const float*)d_in[0];
    const float* coords = (const float*)d_in[1];
    const float* w0     = (const float*)d_in[2];
    const float* b0     = (const float*)d_in[3];
    const float* w1     = (const float*)d_in[4];
    const float* b1     = (const float*)d_in[5];
    const float* w2     = (const float*)d_in[6];
    const float* b2     = (const float*)d_in[7];
    float* out = (float*)d_out;

    const size_t planesTBytes = (size_t)NB * 3 * RES * RES * NCH * 2;   // 50331648
    const size_t w0hBytes = 128 * NCH * 2;                              // 8192
    const size_t w1hBytes = 128 * 128 * 2;                              // 32768
    const size_t needed = planesTBytes + w0hBytes + w1hBytes;

    if (ws_size >= needed) {
        _Float16* planesT = (_Float16*)d_ws;
        _Float16* w0h     = (_Float16*)((char*)d_ws + planesTBytes);
        _Float16* w1h     = (_Float16*)((char*)d_ws + planesTBytes + w0hBytes);

        transpose_prep_kernel<<<dim3(RES, NB * 3 + 1), 256, 0, stream>>>(
            trip, w0, w1, planesT, w0h, w1h);
        fused_kernel<<<(NB * NPT) / 32, 64, 0, stream>>>(
            planesT, coords, w0h, w1h, b0, b1, w2, b2, out);
    } else {
        fused_fallback<<<(NB * NPT) / 256, 256, 0, stream>>>(
            trip, coords, w0, b0, w1, b1, w2, b2, out);
    }
}